// Round 1
// baseline (67.105 us; speedup 1.0000x reference)
//
#include <hip/hip_runtime.h>

// ROI pooling: bilinear resize each (h,w) crop to 7x7 over 256 channels.
// img: (200,200,256) f32 NHWC; rois: (2000,4) int32 (x,y,w,h); out: (2000,7,7,256) f32.
// One 64-lane wave per output cell (roi,py,px); each lane does 4 channels (float4).

__global__ __launch_bounds__(256) void roi_pool_kernel(
    const float* __restrict__ img,
    const int*   __restrict__ rois,
    float*       __restrict__ out,
    int ncells)
{
    constexpr int P = 7;
    constexpr int C = 256;
    constexpr int W = 200;

    const int cell = blockIdx.x * 4 + (threadIdx.x >> 6);   // 4 waves/block, 1 cell/wave
    if (cell >= ncells) return;
    const int c = (threadIdx.x & 63) * 4;                   // channel (x4 per lane)

    const int px = cell % P;
    const int py = (cell / P) % P;
    const int r  = cell / (P * P);

    const int x = rois[4 * r + 0];
    const int y = rois[4 * r + 1];
    const int w = rois[4 * r + 2];
    const int h = rois[4 * r + 3];

    // Axis samples (tf.image.resize bilinear half-pixel semantics), f32 like ref.
    const float sy = (float)h / (float)P;
    const float ty = ((float)py + 0.5f) * sy - 0.5f;
    const float fy = floorf(ty);
    const float wy = ty - fy;
    const int   iy = (int)fy;
    const int   ylo = min(max(iy,     0), h - 1) + y;
    const int   yhi = min(max(iy + 1, 0), h - 1) + y;

    const float sx = (float)w / (float)P;
    const float tx = ((float)px + 0.5f) * sx - 0.5f;
    const float fx = floorf(tx);
    const float wx = tx - fx;
    const int   ix = (int)fx;
    const int   xlo = min(max(ix,     0), w - 1) + x;
    const int   xhi = min(max(ix + 1, 0), w - 1) + x;

    const float* row0 = img + (long)ylo * W * C;
    const float* row1 = img + (long)yhi * W * C;

    const float4 v00 = *(const float4*)(row0 + xlo * C + c);
    const float4 v01 = *(const float4*)(row0 + xhi * C + c);
    const float4 v10 = *(const float4*)(row1 + xlo * C + c);
    const float4 v11 = *(const float4*)(row1 + xhi * C + c);

    float4 res;
    {
        float t0 = v00.x + (v01.x - v00.x) * wx;
        float b0 = v10.x + (v11.x - v10.x) * wx;
        res.x = t0 + (b0 - t0) * wy;
        float t1 = v00.y + (v01.y - v00.y) * wx;
        float b1 = v10.y + (v11.y - v10.y) * wx;
        res.y = t1 + (b1 - t1) * wy;
        float t2 = v00.z + (v01.z - v00.z) * wx;
        float b2 = v10.z + (v11.z - v10.z) * wx;
        res.z = t2 + (b2 - t2) * wy;
        float t3 = v00.w + (v01.w - v00.w) * wx;
        float b3 = v10.w + (v11.w - v10.w) * wx;
        res.w = t3 + (b3 - t3) * wy;
    }

    *(float4*)(out + (long)cell * C + c) = res;
}

extern "C" void kernel_launch(void* const* d_in, const int* in_sizes, int n_in,
                              void* d_out, int out_size, void* d_ws, size_t ws_size,
                              hipStream_t stream) {
    const float* img  = (const float*)d_in[0];
    const int*   rois = (const int*)d_in[1];
    float*       out  = (float*)d_out;

    const int R      = in_sizes[1] / 4;   // 2000
    const int ncells = R * 7 * 7;         // 98000
    const int blocks = (ncells + 3) / 4;  // 4 cells (waves) per block

    roi_pool_kernel<<<blocks, 256, 0, stream>>>(img, rois, out, ncells);
}